// Round 11
// baseline (105.455 us; speedup 1.0000x reference)
//
#include <hip/hip_runtime.h>
#include <hip/hip_bf16.h>

#define J_JOINTS 17
#define ROW_F 51                 // floats per row per array
#define BLOCK 256
#define GRID 2048                // grid-stride; 8192 waves, 32 waves/CU
#define ROWS_PER_GROUP 16        // one wave-iteration: 16 rows, 4 lanes/row

struct __align__(4) F3 { float x, y, z; };

__global__ __launch_bounds__(BLOCK) void loss_main_kernel(
    const float* __restrict__ outp,   // (B, 17, 3)
    const float* __restrict__ tgt,    // (B, 17, 3)
    double* __restrict__ acc,         // acc[0]=cls_sum, acc[1]=reg_sum
    int B)
{
    const int tid = threadIdx.x;
    const int wv  = tid >> 6;
    const int ln  = tid & 63;
    const int r   = ln >> 2;    // row within group (0..15)
    const int q   = ln & 3;     // joint quarter: joints 4q..4q+3 (+16 if q==3)

    float cls_acc = 0.0f;
    float reg_acc = 0.0f;

    const int groups = B / ROWS_PER_GROUP;               // full 16-row groups
    const int W      = GRID * (BLOCK / 64);              // total waves = 8192
    const int gw     = (int)blockIdx.x * (BLOCK / 64) + wv;

    for (int gidx = gw; gidx < groups; gidx += W) {
        const int row = gidx * ROWS_PER_GROUP + r;
        // this lane's 12-float segment (4 joints), direct from global via L1
        const float* po = outp + row * ROW_F + q * 12;
        const float* pt = tgt  + row * ROW_F + q * 12;

        float sq = 0.0f;
        float nj = 0.0f;

        #pragma unroll
        for (int k = 0; k < 4; ++k) {
            const F3 o = *reinterpret_cast<const F3*>(po + 3 * k);
            const F3 t = *reinterpret_cast<const F3*>(pt + 3 * k);

            const bool gt1 = (t.z == 1.0f);
            cls_acc += fmaxf(__logf(gt1 ? o.z : (1.0f - o.z)), -100.0f);

            const bool keep = (o.z >= 0.5f);
            const float d0 = keep ? (o.x - t.x) : 0.0f;
            const float d1 = keep ? (o.y - t.y) : 0.0f;
            sq = fmaf(d0, d0, fmaf(d1, d1, sq));
            nj += gt1 ? 1.0f : 0.0f;
        }
        if (q == 3) {   // joint 16: floats 48..50 of the row = po + 12
            const F3 o = *reinterpret_cast<const F3*>(po + 12);
            const F3 t = *reinterpret_cast<const F3*>(pt + 12);

            const bool gt1 = (t.z == 1.0f);
            cls_acc += fmaxf(__logf(gt1 ? o.z : (1.0f - o.z)), -100.0f);

            const bool keep = (o.z >= 0.5f);
            const float d0 = keep ? (o.x - t.x) : 0.0f;
            const float d1 = keep ? (o.y - t.y) : 0.0f;
            sq = fmaf(d0, d0, fmaf(d1, d1, sq));
            nj += gt1 ? 1.0f : 0.0f;
        }

        // segmented reduce across the 4-lane row group
        sq += __shfl_xor(sq, 1, 64);  nj += __shfl_xor(nj, 1, 64);
        sq += __shfl_xor(sq, 2, 64);  nj += __shfl_xor(nj, 2, 64);
        if (q == 0) {
            reg_acc += __fdividef(0.5f * sq, 1.0f + nj);
        }
    }

    // ---- generic tail rows (B % 16 != 0) ----
    const int tail0 = groups * ROWS_PER_GROUP;
    if (blockIdx.x == 0 && tid < (B - tail0)) {
        const int b = tail0 + tid;
        float sq = 0.f, nj = 0.f;
        for (int j = 0; j < J_JOINTS; ++j) {
            const int base = b * ROW_F + 3 * j;
            const F3 o = *reinterpret_cast<const F3*>(outp + base);
            const F3 t = *reinterpret_cast<const F3*>(tgt + base);
            const bool gt1 = (t.z == 1.0f);
            cls_acc += fmaxf(__logf(gt1 ? o.z : (1.0f - o.z)), -100.0f);
            const bool keep = (o.z >= 0.5f);
            const float d0 = keep ? (o.x - t.x) : 0.0f;
            const float d1 = keep ? (o.y - t.y) : 0.0f;
            sq = fmaf(d0, d0, fmaf(d1, d1, sq));
            nj += gt1 ? 1.0f : 0.0f;
        }
        reg_acc += __fdividef(0.5f * sq, 1.0f + nj);
    }

    // ---- block reduction (cold path) ----
    #pragma unroll
    for (int m = 1; m < 64; m <<= 1) {
        cls_acc += __shfl_xor(cls_acc, m, 64);
        reg_acc += __shfl_xor(reg_acc, m, 64);
    }
    __shared__ float s_cls[BLOCK / 64];
    __shared__ float s_reg[BLOCK / 64];
    if (ln == 0) {
        s_cls[wv] = cls_acc;
        s_reg[wv] = reg_acc;
    }
    __syncthreads();
    if (tid == 0) {
        float c = 0.0f, rr = 0.0f;
        #pragma unroll
        for (int w = 0; w < BLOCK / 64; ++w) { c += s_cls[w]; rr += s_reg[w]; }
        atomicAdd(&acc[0], (double)c);
        atomicAdd(&acc[1], (double)rr);
    }
}

__global__ void loss_finalize_kernel(const double* __restrict__ acc,
                                     float* __restrict__ out, int B)
{
    const double cls_sum = acc[0];
    const double reg_sum = acc[1];
    const double loss_class = -cls_sum / ((double)B * (double)J_JOINTS);
    const double loss_reg   = reg_sum / (double)B;
    out[0] = (float)(loss_class + loss_reg);
}

extern "C" void kernel_launch(void* const* d_in, const int* in_sizes, int n_in,
                              void* d_out, int out_size, void* d_ws, size_t ws_size,
                              hipStream_t stream) {
    const float* outp = (const float*)d_in[0];
    const float* tgt  = (const float*)d_in[1];
    float* out = (float*)d_out;
    const int B = in_sizes[0] / (J_JOINTS * 3);

    double* acc = (double*)d_ws;
    hipMemsetAsync(acc, 0, 2 * sizeof(double), stream);

    loss_main_kernel<<<GRID, BLOCK, 0, stream>>>(outp, tgt, acc, B);
    loss_finalize_kernel<<<1, 1, 0, stream>>>(acc, out, B);
}

// Round 12
// 98.652 us; speedup vs baseline: 1.0690x; 1.0690x over previous
//
#include <hip/hip_runtime.h>
#include <hip/hip_bf16.h>
#include <stdint.h>

#define J_JOINTS 17
#define ROW_F 51                         // floats per row per array
#define BLOCK 256
#define TILE_ROWS 64                     // rows per tile; 4 threads/row
#define TILE_F (TILE_ROWS * ROW_F)       // 3264 floats per tile (tgt only)
#define TILE_CHUNKS (TILE_F / 4)         // 816 16B chunks per tile
#define GRID 1536                        // 6 blocks/CU (26 KB LDS each)

struct __align__(4) F3 { float x, y, z; };

__device__ __forceinline__ void gld_lds16(const float* g, float* l) {
    // async global -> LDS; HW dest = wave-uniform base + lane*16
    __builtin_amdgcn_global_load_lds(
        (const __attribute__((address_space(1))) void*)g,
        (__attribute__((address_space(3))) void*)l,
        16, 0, 0);
}

__global__ __launch_bounds__(BLOCK) void loss_main_kernel(
    const float* __restrict__ outp,   // (B, 17, 3)  -- read DIRECT via L1
    const float* __restrict__ tgt,    // (B, 17, 3)  -- staged via LDS-DMA
    double* __restrict__ acc,         // acc[0]=cls_sum, acc[1]=reg_sum
    int B)
{
    __shared__ float st[2][TILE_F];   // 2 x 13056 B = 26112 B -> 6 blocks/CU

    const int tid = threadIdx.x;
    const int wv  = tid >> 6;
    const int ln  = tid & 63;
    const int r4  = tid >> 2;   // local row (0..63)
    const int q   = tid & 3;    // joint quarter: joints 4q..4q+3 (+16 if q==3)

    float cls_acc = 0.0f;
    float reg_acc = 0.0f;

    const int tiles_total = (B + TILE_ROWS - 1) / TILE_ROWS;

    // stage tgt tile (async DMA, linear LDS dest)
    auto stage_async = [&](int row0, int buf) {
        const float* gt = tgt + row0 * ROW_F;
        float* lt = st[buf];
        #pragma unroll
        for (int j = 0; j < 4; ++j) {
            const int i = tid + j * BLOCK;
            if (i < TILE_CHUNKS) {
                gld_lds16(gt + i * 4, lt + i * 4);
            }
        }
    };
    // partial-tile fallback (sync loads)
    auto stage_sync = [&](int row0, int rows_valid, int buf) {
        const float* gt = tgt + row0 * ROW_F;
        const int nv = rows_valid * ROW_F;
        const int n4 = nv >> 2;
        for (int i = tid; i < n4; i += BLOCK) {
            reinterpret_cast<float4*>(st[buf])[i] = reinterpret_cast<const float4*>(gt)[i];
        }
        const int tb = n4 << 2;
        if (tid < nv - tb) {
            st[buf][tb + tid] = gt[tb + tid];
        }
    };
    auto stage = [&](int tk, int buf) {
        const int row0 = tk * TILE_ROWS;
        if (row0 + TILE_ROWS <= B) stage_async(row0, buf);
        else                       stage_sync(row0, B - row0, buf);
    };

    // ---- pipeline: DMA(t+1) in flight while computing t (R4-proven sync) ----
    int tk  = blockIdx.x;
    int cur = 0;

    if (tk < tiles_total) stage(tk, 0);
    asm volatile("s_waitcnt vmcnt(0)" ::: "memory");
    __syncthreads();

    while (tk < tiles_total) {
        const int tn = tk + GRID;
        if (tn < tiles_total) stage(tn, cur ^ 1);

        // ---- compute tile tk: outp direct from global, tgt from LDS ----
        const int rows_valid = min(TILE_ROWS, B - tk * TILE_ROWS);
        float sq = 0.0f;
        float nj = 0.0f;
        if (r4 < rows_valid) {
            const int row_g = tk * TILE_ROWS + r4;
            const float* po = outp + row_g * ROW_F + q * 12;   // direct
            const float* lt = &st[cur][r4 * ROW_F + q * 12];   // LDS
            #pragma unroll
            for (int k = 0; k < 4; ++k) {
                const F3 o = *reinterpret_cast<const F3*>(po + 3 * k);
                const float tx = lt[3*k + 0];
                const float ty = lt[3*k + 1];
                const float tz = lt[3*k + 2];

                const bool gt1 = (tz == 1.0f);
                cls_acc += fmaxf(__logf(gt1 ? o.z : (1.0f - o.z)), -100.0f);

                const bool keep = (o.z >= 0.5f);
                const float d0 = keep ? (o.x - tx) : 0.0f;
                const float d1 = keep ? (o.y - ty) : 0.0f;
                sq = fmaf(d0, d0, fmaf(d1, d1, sq));
                nj += gt1 ? 1.0f : 0.0f;
            }
            if (q == 3) {   // joint 16: 12 floats past q*12=36
                const F3 o = *reinterpret_cast<const F3*>(po + 12);
                const float tx = lt[12 + 0];
                const float ty = lt[12 + 1];
                const float tz = lt[12 + 2];

                const bool gt1 = (tz == 1.0f);
                cls_acc += fmaxf(__logf(gt1 ? o.z : (1.0f - o.z)), -100.0f);

                const bool keep = (o.z >= 0.5f);
                const float d0 = keep ? (o.x - tx) : 0.0f;
                const float d1 = keep ? (o.y - ty) : 0.0f;
                sq = fmaf(d0, d0, fmaf(d1, d1, sq));
                nj += gt1 ? 1.0f : 0.0f;
            }
        }
        // segmented reduce across the 4-lane row group
        sq += __shfl_xor(sq, 1, 64);  nj += __shfl_xor(nj, 1, 64);
        sq += __shfl_xor(sq, 2, 64);  nj += __shfl_xor(nj, 2, 64);
        if (q == 0 && r4 < rows_valid) {
            reg_acc += __fdividef(0.5f * sq, 1.0f + nj);
        }

        // drain next-tile DMA + protect LDS buffers (proven R4 discipline)
        asm volatile("s_waitcnt vmcnt(0)" ::: "memory");
        __syncthreads();
        cur ^= 1;
        tk = tn;
    }

    // ---- block reduction ----
    #pragma unroll
    for (int m = 1; m < 64; m <<= 1) {
        cls_acc += __shfl_xor(cls_acc, m, 64);
        reg_acc += __shfl_xor(reg_acc, m, 64);
    }
    __shared__ float s_cls[BLOCK / 64];
    __shared__ float s_reg[BLOCK / 64];
    if (ln == 0) {
        s_cls[wv] = cls_acc;
        s_reg[wv] = reg_acc;
    }
    __syncthreads();
    if (tid == 0) {
        float c = 0.0f, r = 0.0f;
        #pragma unroll
        for (int w = 0; w < BLOCK / 64; ++w) { c += s_cls[w]; r += s_reg[w]; }
        atomicAdd(&acc[0], (double)c);
        atomicAdd(&acc[1], (double)r);
    }
}

__global__ void loss_finalize_kernel(const double* __restrict__ acc,
                                     float* __restrict__ out, int B)
{
    const double cls_sum = acc[0];
    const double reg_sum = acc[1];
    const double loss_class = -cls_sum / ((double)B * (double)J_JOINTS);
    const double loss_reg   = reg_sum / (double)B;
    out[0] = (float)(loss_class + loss_reg);
}

extern "C" void kernel_launch(void* const* d_in, const int* in_sizes, int n_in,
                              void* d_out, int out_size, void* d_ws, size_t ws_size,
                              hipStream_t stream) {
    const float* outp = (const float*)d_in[0];
    const float* tgt  = (const float*)d_in[1];
    float* out = (float*)d_out;
    const int B = in_sizes[0] / (J_JOINTS * 3);

    double* acc = (double*)d_ws;
    hipMemsetAsync(acc, 0, 2 * sizeof(double), stream);

    loss_main_kernel<<<GRID, BLOCK, 0, stream>>>(outp, tgt, acc, B);
    loss_finalize_kernel<<<1, 1, 0, stream>>>(acc, out, B);
}